// Round 12
// baseline (471.137 us; speedup 1.0000x reference)
//
#include <hip/hip_runtime.h>
#include <stdint.h>

#define TPB 1024
#define NL 4

typedef _Float16 f16;
typedef _Float16 half2v __attribute__((ext_vector_type(2)));
typedef _Float16 f16x8 __attribute__((ext_vector_type(8)));
typedef float f32x4 __attribute__((ext_vector_type(4)));
typedef uint32_t u32x2 __attribute__((ext_vector_type(2)));
typedef uint32_t u32x4 __attribute__((ext_vector_type(4)));

// X2 u32 index for row r, u32-col c: 16B-block XOR swizzle (block ^= row&7).
#define XIU(r, c) ((r) * 32 + (((((c) >> 2) ^ ((r) & 7))) << 2) + ((c) & 3))

static __device__ __forceinline__ uint32_t packh2(float a, float b) {
  half2v h;
  h.x = (_Float16)a;
  h.y = (_Float16)b;
  return __builtin_bit_cast(uint32_t, h);
}
static __device__ __forceinline__ float2 unpackh2(uint32_t u) {
  half2v h = __builtin_bit_cast(half2v, u);
  return make_float2((float)h.x, (float)h.y);
}

__global__ void pack_weights_kernel(const float* __restrict__ ff1_w,
                                    const float* __restrict__ ff2_w,
                                    f16* __restrict__ w1h,
                                    f16* __restrict__ w2h,
                                    float* __restrict__ petab) {
  int idx = blockIdx.x * blockDim.x + threadIdx.x;
  if (idx < 16384) {
    w1h[idx] = (f16)ff1_w[idx];
  } else if (idx < 32768) {
    w2h[idx - 16384] = (f16)ff2_w[idx - 16384];
  } else if (petab != nullptr && idx < 32768 + 64000) {
    int j = idx - 32768;
    int s = j >> 6, d = j & 63;
    float div = exp2f(-0.4152410118609203f * (float)(d >> 1));
    float ang = (float)s * div;
    petab[j] = (d & 1) ? cosf(ang) : sinf(ang);
  }
}

// R12 = R11 (correct, best conflicts 7.3e6) + pointer LAUNDERING to kill the
// LICM weight-hoist that caused R11's 282 MB spill: the FF macros' weight/
// bias/gamma loads are rg-invariant, so LICM hoisted ~90 regs of loads out of
// the rg loop at the backend's immovable 64-VGPR allocation -> spill. An
// asm volatile("" : "+s"(ptr)) at the top of each rg iteration redefines the
// pointers per-iteration: loads stay inside their sched_barrier(0)-fenced
// tiles (~25 transient regs live). No semantic change.
__global__ __launch_bounds__(TPB) void aat_kernel(
    const int* __restrict__ tokens, const float* __restrict__ emb,
    const float* __restrict__ lin_w, const float* __restrict__ lin_b,
    const float* __restrict__ ff1_b, const float* __restrict__ ff2_b,
    const float* __restrict__ n1_g, const float* __restrict__ n1_b,
    const float* __restrict__ n2_g, const float* __restrict__ n2_b,
    const float* __restrict__ out_w, const float* __restrict__ out_b,
    const f16* __restrict__ w1h, const f16* __restrict__ w2h,
    const float* __restrict__ petab, float* __restrict__ out) {
  __shared__ uint32_t X2[1000 * 32];      // 128000 B, swizzled rows (f16 pairs)
  __shared__ uint32_t Hreg[16 * 512];     // 32768 B: per-wave H [16][32] / avg redbuf
  __shared__ float avgbuf[64];
  __shared__ __align__(8) float attnbuf[64];

  const int t = threadIdx.x;
  const int b = blockIdx.x;
  const int lane = t & 63;
  const int wv = t >> 6;                  // 0..15
  const bool valid = (t < 1000);
  float* redbuf = (float*)Hreg;           // [32][64] f32 during avg phase

  // ---------------- embed * sqrt(d) + positional encoding -> X2 ----------------
  if (valid) {
    int tok = tokens[b * 1000 + t];
    const float4* ev = (const float4*)(emb + (size_t)tok * 64);
    const int r7 = t & 7;
    if (petab != nullptr) {
      const float4* pv = (const float4*)(petab + (size_t)t * 64);
      #pragma unroll
      for (int q = 0; q < 8; q++) {
        float4 v0 = ev[2 * q], v1 = ev[2 * q + 1];
        float4 p0 = pv[2 * q], p1 = pv[2 * q + 1];
        u32x4 w;
        w[0] = packh2(fmaf(v0.x, 8.f, p0.x), fmaf(v0.y, 8.f, p0.y));
        w[1] = packh2(fmaf(v0.z, 8.f, p0.z), fmaf(v0.w, 8.f, p0.w));
        w[2] = packh2(fmaf(v1.x, 8.f, p1.x), fmaf(v1.y, 8.f, p1.y));
        w[3] = packh2(fmaf(v1.z, 8.f, p1.z), fmaf(v1.w, 8.f, p1.w));
        *(u32x4*)(&X2[t * 32 + ((q ^ r7) << 2)]) = w;
      }
    } else {
      float fs = (float)t;
      #pragma unroll
      for (int q = 0; q < 8; q++) {
        float4 v0 = ev[2 * q], v1 = ev[2 * q + 1];
        float d0 = exp2f(-0.4152410118609203f * (float)(4 * q));
        float d1 = exp2f(-0.4152410118609203f * (float)(4 * q + 1));
        float d2 = exp2f(-0.4152410118609203f * (float)(4 * q + 2));
        float d3 = exp2f(-0.4152410118609203f * (float)(4 * q + 3));
        u32x4 w;
        w[0] = packh2(fmaf(v0.x, 8.f, sinf(fs * d0)), fmaf(v0.y, 8.f, cosf(fs * d0)));
        w[1] = packh2(fmaf(v0.z, 8.f, sinf(fs * d1)), fmaf(v0.w, 8.f, cosf(fs * d1)));
        w[2] = packh2(fmaf(v1.x, 8.f, sinf(fs * d2)), fmaf(v1.y, 8.f, cosf(fs * d2)));
        w[3] = packh2(fmaf(v1.z, 8.f, sinf(fs * d3)), fmaf(v1.w, 8.f, cosf(fs * d3)));
        *(u32x4*)(&X2[t * 32 + ((q ^ r7) << 2)]) = w;
      }
    }
  }
  __syncthreads();

  const int l15 = lane & 15;
  const int g4 = lane >> 4;               // 0..3
  const int e7 = l15 & 7;                 // == (FF row s) & 7 for this lane
  uint32_t* hw = Hreg + wv * 512;         // per-wave H slice [16][32], swizzled

  #pragma unroll 1
  for (int l = 0; l < NL; l++) {
    const float* n1g = n1_g + l * 64;
    const float* n1b = n1_b + l * 64;
    const float* n2gl = n2_g + l * 64;
    const float* n2bl = n2_b + l * 64;
    const float* f1b = ff1_b + l * 64;
    const float* f2b = ff2_b + l * 64;
    const f16* w1l = w1h + l * 4096;
    const f16* w2l = w2h + l * 4096;

    // ------- avg over sequence: column-parallel partials into redbuf -------
    {
      int cp = t & 31, rg = t >> 5;
      float s0 = 0.f, s1 = 0.f;
      for (int r = rg; r < 1000; r += 32) {
        float2 v = unpackh2(X2[XIU(r, cp)]);
        s0 += v.x;
        s1 += v.y;
      }
      redbuf[rg * 64 + 2 * cp] = s0;
      redbuf[rg * 64 + 2 * cp + 1] = s1;
    }
    __syncthreads();                       // barrier 1: redbuf complete
    if (t < 64) {
      float ssum = 0.f;
      #pragma unroll
      for (int w = 0; w < 32; w++) ssum += redbuf[w * 64 + t];
      avgbuf[t] = ssum * 1e-3f;
    }
    if (t < 64) {  // attn[o] = lin_b[o] + sum_d avg[d]*lin_w[o][d] (wave0-local)
      const float* wr = lin_w + (size_t)(l * 64 + t) * 64;
      float a0 = lin_b[l * 64 + t], a1 = 0.f, a2 = 0.f, a3 = 0.f;
      #pragma unroll
      for (int d = 0; d < 64; d += 4) {
        a0 += avgbuf[d] * wr[d];
        a1 += avgbuf[d + 1] * wr[d + 1];
        a2 += avgbuf[d + 2] * wr[d + 2];
        a3 += avgbuf[d + 3] * wr[d + 3];
      }
      attnbuf[t] = (a0 + a1) + (a2 + a3);
    }
    __syncthreads();                       // barrier 2: attnbuf visible to all

    // ---------------- LN1 (thread t = row t): Y overwrites X2 ----------------
    if (valid) {
      const float2* at2 = (const float2*)attnbuf;
      const int r7 = t & 7;
      float m0 = 0.f, q0 = 0.f;
      #pragma unroll
      for (int q = 0; q < 8; q++) {
        u32x4 w = *(const u32x4*)(&X2[t * 32 + ((q ^ r7) << 2)]);
        #pragma unroll
        for (int j = 0; j < 4; j++) {
          float2 xv = unpackh2(w[j]);
          float2 at = at2[q * 4 + j];
          float a0 = xv.x + at.x, a1 = xv.y + at.y;
          m0 += a0 + a1;
          q0 = fmaf(a0, a0, q0);
          q0 = fmaf(a1, a1, q0);
        }
      }
      float mu = m0 * (1.0f / 64.0f);
      float var = q0 * (1.0f / 64.0f) - mu * mu;
      float rs = rsqrtf(var + 1e-5f);
      #pragma unroll
      for (int q = 0; q < 8; q++) {
        u32x4 w = *(const u32x4*)(&X2[t * 32 + ((q ^ r7) << 2)]);
        u32x4 o;
        #pragma unroll
        for (int j = 0; j < 4; j++) {
          float2 xv = unpackh2(w[j]);
          float2 at = at2[q * 4 + j];
          int d = (q * 4 + j) * 2;
          float a0 = xv.x + at.x, a1 = xv.y + at.y;
          o[j] = packh2(fmaf((a0 - mu) * rs, n1g[d], n1b[d]),
                        fmaf((a1 - mu) * rs, n1g[d + 1], n1b[d + 1]));
        }
        *(u32x4*)(&X2[t * 32 + ((q ^ r7) << 2)]) = o;
      }
    }
    // no barrier: each wave's FF touches only its own 64 rows.

    // ---------------- FF: wave-private, swapped MFMA, tile-serial ----------------
    #pragma unroll 1
    for (int rg = 0; rg < 4; rg++) {
      // LAUNDER loop-invariant pointers: defeats LICM's hoist of all 8 weight
      // tiles + bias/param quads (the R9/R11 spill mechanism).
      const f16* w1r = w1l;
      const f16* w2r = w2l;
      const float* f1r = f1b;
      const float* f2r = f2b;
      const float* g2r = n2gl;
      const float* b2r = n2bl;
      asm volatile("" : "+s"(w1r), "+s"(w2r), "+s"(f1r), "+s"(f2r),
                        "+s"(g2r), "+s"(b2r));

      const int s = wv * 64 + rg * 16 + l15;   // this lane's seq row (B-col)
      const int sbase = s * 32;
      // B1 = Y^T fragments: two b128 reads
      u32x4 b1q0 = *(const u32x4*)(&X2[sbase + ((g4 ^ e7) << 2)]);
      u32x4 b1q1 = *(const u32x4*)(&X2[sbase + (((4 + g4) ^ e7) << 2)]);
      f16x8 B1k0 = __builtin_bit_cast(f16x8, b1q0);
      f16x8 B1k1 = __builtin_bit_cast(f16x8, b1q1);

      // ---- mm1: H^T = W1 * Y^T, 4 tiles, write H to per-wave LDS (b64) ----
#define MM1T(OT) { \
      const f16* ap = w1r + (16 * (OT) + l15) * 64 + 8 * g4; \
      f16x8 A0 = *(const f16x8*)(ap); \
      f16x8 A1 = *(const f16x8*)(ap + 32); \
      f32x4 acc = *(const f32x4*)(f1r + 16 * (OT) + 4 * g4); \
      acc = __builtin_amdgcn_mfma_f32_16x16x32_f16(A0, B1k0, acc, 0, 0, 0); \
      acc = __builtin_amdgcn_mfma_f32_16x16x32_f16(A1, B1k1, acc, 0, 0, 0); \
      u32x2 hp; \
      hp[0] = packh2(fmaxf(acc[0], 0.f), fmaxf(acc[1], 0.f)); \
      hp[1] = packh2(fmaxf(acc[2], 0.f), fmaxf(acc[3], 0.f)); \
      *(u32x2*)(&hw[l15 * 32 + (((2 * (OT) + (g4 >> 1)) ^ e7) << 2) + 2 * (g4 & 1)]) = hp; }
      MM1T(0)
      __builtin_amdgcn_sched_barrier(0);
      MM1T(1)
      __builtin_amdgcn_sched_barrier(0);
      MM1T(2)
      __builtin_amdgcn_sched_barrier(0);
      MM1T(3)
      __builtin_amdgcn_sched_barrier(0);
#undef MM1T

      // B2 = H fragments: two b128 reads (same-wave data)
      u32x4 h0 = *(const u32x4*)(&hw[l15 * 32 + ((g4 ^ e7) << 2)]);
      u32x4 h1 = *(const u32x4*)(&hw[l15 * 32 + (((4 + g4) ^ e7) << 2)]);
      f16x8 B2k0 = __builtin_bit_cast(f16x8, h0);
      f16x8 B2k1 = __builtin_bit_cast(f16x8, h1);

      // ---- mm2: T^T = W2 * H + b2 + Y, tile-serial, T packed to 8 u32 ----
      float sum = 0.f, sq = 0.f;
      u32x2 tp0, tp1, tp2, tp3;
#define MM2T(OT, TP) { \
      const f16* ap = w2r + (16 * (OT) + l15) * 64 + 8 * g4; \
      f16x8 A0 = *(const f16x8*)(ap); \
      f16x8 A1 = *(const f16x8*)(ap + 32); \
      u32x2 ry = *(const u32x2*)(&X2[sbase + (((2 * (OT) + (g4 >> 1)) ^ e7) << 2) + 2 * (g4 & 1)]); \
      float2 r0 = unpackh2(ry[0]), r1 = unpackh2(ry[1]); \
      f32x4 acc = *(const f32x4*)(f2r + 16 * (OT) + 4 * g4); \
      acc[0] += r0.x; acc[1] += r0.y; acc[2] += r1.x; acc[3] += r1.y; \
      acc = __builtin_amdgcn_mfma_f32_16x16x32_f16(A0, B2k0, acc, 0, 0, 0); \
      acc = __builtin_amdgcn_mfma_f32_16x16x32_f16(A1, B2k1, acc, 0, 0, 0); \
      sum += (acc[0] + acc[1]) + (acc[2] + acc[3]); \
      sq = fmaf(acc[0], acc[0], sq); sq = fmaf(acc[1], acc[1], sq); \
      sq = fmaf(acc[2], acc[2], sq); sq = fmaf(acc[3], acc[3], sq); \
      TP[0] = packh2(acc[0], acc[1]); TP[1] = packh2(acc[2], acc[3]); }
      MM2T(0, tp0)
      __builtin_amdgcn_sched_barrier(0);
      MM2T(1, tp1)
      __builtin_amdgcn_sched_barrier(0);
      MM2T(2, tp2)
      __builtin_amdgcn_sched_barrier(0);
      MM2T(3, tp3)
#undef MM2T

      // ---- in-register LN2: row sums across the 4 g4-lanes of row s ----
      sum += __shfl_xor(sum, 16, 64);
      sum += __shfl_xor(sum, 32, 64);
      sq += __shfl_xor(sq, 16, 64);
      sq += __shfl_xor(sq, 32, 64);
      float mu2 = sum * (1.0f / 64.0f);
      float var2 = sq * (1.0f / 64.0f) - mu2 * mu2;
      float rs2 = rsqrtf(var2 + 1e-5f);
      if (s < 1000) {
#define WBT(OT, TP) { \
        f32x4 gg = *(const f32x4*)(g2r + 16 * (OT) + 4 * g4); \
        f32x4 bb = *(const f32x4*)(b2r + 16 * (OT) + 4 * g4); \
        float2 v0 = unpackh2(TP[0]), v1 = unpackh2(TP[1]); \
        u32x2 xw; \
        xw[0] = packh2(fmaf((v0.x - mu2) * rs2, gg[0], bb[0]), \
                       fmaf((v0.y - mu2) * rs2, gg[1], bb[1])); \
        xw[1] = packh2(fmaf((v1.x - mu2) * rs2, gg[2], bb[2]), \
                       fmaf((v1.y - mu2) * rs2, gg[3], bb[3])); \
        *(u32x2*)(&X2[sbase + (((2 * (OT) + (g4 >> 1)) ^ e7) << 2) + 2 * (g4 & 1)]) = xw; }
        WBT(0, tp0) WBT(1, tp1) WBT(2, tp2) WBT(3, tp3)
#undef WBT
      }
    }
    __syncthreads();                       // barrier 3: layer complete
  }

  // ---------------- output projection [B,S,2] ----------------
  if (valid) {
    const int r7 = t & 7;
    float a0 = out_b[0], a1 = out_b[1];
    #pragma unroll
    for (int q = 0; q < 8; q++) {
      u32x4 w = *(const u32x4*)(&X2[t * 32 + ((q ^ r7) << 2)]);
      #pragma unroll
      for (int j = 0; j < 4; j++) {
        float2 xv = unpackh2(w[j]);
        int d = (q * 4 + j) * 2;
        a0 += xv.x * out_w[d] + xv.y * out_w[d + 1];
        a1 += xv.x * out_w[64 + d] + xv.y * out_w[64 + d + 1];
      }
    }
    *(float2*)(out + (size_t)(b * 1000 + t) * 2) = make_float2(a0, a1);
  }
}

extern "C" void kernel_launch(void* const* d_in, const int* in_sizes, int n_in,
                              void* d_out, int out_size, void* d_ws, size_t ws_size,
                              hipStream_t stream) {
  const int* tokens = (const int*)d_in[0];
  const float* emb = (const float*)d_in[1];
  const float* lin_w = (const float*)d_in[2];
  const float* lin_b = (const float*)d_in[3];
  const float* ff1_w = (const float*)d_in[4];
  const float* ff1_b = (const float*)d_in[5];
  const float* ff2_w = (const float*)d_in[6];
  const float* ff2_b = (const float*)d_in[7];
  const float* n1_g = (const float*)d_in[8];
  const float* n1_b = (const float*)d_in[9];
  const float* n2_g = (const float*)d_in[10];
  const float* n2_b = (const float*)d_in[11];
  const float* out_w = (const float*)d_in[12];
  const float* out_b = (const float*)d_in[13];
  float* out = (float*)d_out;

  f16* w1h = (f16*)d_ws;                         // 32 KiB
  f16* w2h = w1h + 16384;                        // 32 KiB
  float* petab = (float*)((char*)d_ws + 65536);  // 250 KiB (1000*64 f32)
  const size_t need = 65536 + 64000 * 4;
  const bool use_pe = (ws_size >= need);
  float* pe_arg = use_pe ? petab : nullptr;

  int pack_threads = 32768 + (use_pe ? 64000 : 0);
  int pack_blocks = (pack_threads + 255) / 256;
  pack_weights_kernel<<<pack_blocks, 256, 0, stream>>>(ff1_w, ff2_w, w1h, w2h, pe_arg);
  aat_kernel<<<512, TPB, 0, stream>>>(tokens, emb, lin_w, lin_b, ff1_b, ff2_b,
                                      n1_g, n1_b, n2_g, n2_b, out_w, out_b,
                                      w1h, w2h, pe_arg, out);
}

// Round 13
// 280.828 us; speedup vs baseline: 1.6777x; 1.6777x over previous
//
#include <hip/hip_runtime.h>
#include <stdint.h>

#define TPB 1024
#define NL 4

typedef _Float16 f16;
typedef _Float16 half2v __attribute__((ext_vector_type(2)));
typedef _Float16 f16x8 __attribute__((ext_vector_type(8)));
typedef float f32x4 __attribute__((ext_vector_type(4)));
typedef uint32_t u32x2 __attribute__((ext_vector_type(2)));
typedef uint32_t u32x4 __attribute__((ext_vector_type(4)));

// X2/Hreg u32 index for row r, u32-col c: 16B-block XOR swizzle (block ^= r&7).
#define XIU(r, c) ((r) * 32 + (((((c) >> 2) ^ ((r) & 7))) << 2) + ((c) & 3))

static __device__ __forceinline__ uint32_t packh2(float a, float b) {
  half2v h;
  h.x = (_Float16)a;
  h.y = (_Float16)b;
  return __builtin_bit_cast(uint32_t, h);
}
static __device__ __forceinline__ float2 unpackh2(uint32_t u) {
  half2v h = __builtin_bit_cast(half2v, u);
  return make_float2((float)h.x, (float)h.y);
}

__global__ void pack_weights_kernel(const float* __restrict__ ff1_w,
                                    const float* __restrict__ ff2_w,
                                    f16* __restrict__ w1h,
                                    f16* __restrict__ w2h,
                                    float* __restrict__ petab) {
  int idx = blockIdx.x * blockDim.x + threadIdx.x;
  if (idx < 16384) {
    w1h[idx] = (f16)ff1_w[idx];
  } else if (idx < 32768) {
    w2h[idx - 16384] = (f16)ff2_w[idx - 16384];
  } else if (petab != nullptr && idx < 32768 + 64000) {
    int j = idx - 32768;
    int s = j >> 6, d = j & 63;
    float div = exp2f(-0.4152410118609203f * (float)(d >> 1));
    float ang = (float)s * div;
    petab[j] = (d & 1) ? cosf(ang) : sinf(ang);
  }
}

// R13: 2-D wave split (mr,nt) resolves the R9..R12 weight-register tension.
// Each wave holds ONLY its nt-tile of W1/W2 (16 VGPR + 8 bias) hoisted per
// layer by LICM -- the exact behavior that caused R11's spill now fits the
// backend's immovable 64-VGPR budget. No laundering, no sched fences; FF
// inner loop is pure LDS-b128 + MFMA (R11's verified fragment layouts and
// best-measured swizzle, 7.3e6 conflicts). H crosses waves -> chunked FF
// (256 rows, Hreg 32KB) with 2 barriers/chunk; LN2 = thread-per-row (R8
// code). 12 barriers/layer. X2 padded to 1024 rows; avg/attn bufs unioned
// into Hreg; LDS = exactly 160 KiB (1 block/CU, 4 waves/SIMD).
__global__ __launch_bounds__(TPB) void aat_kernel(
    const int* __restrict__ tokens, const float* __restrict__ emb,
    const float* __restrict__ lin_w, const float* __restrict__ lin_b,
    const float* __restrict__ ff1_b, const float* __restrict__ ff2_b,
    const float* __restrict__ n1_g, const float* __restrict__ n1_b,
    const float* __restrict__ n2_g, const float* __restrict__ n2_b,
    const float* __restrict__ out_w, const float* __restrict__ out_b,
    const f16* __restrict__ w1h, const f16* __restrict__ w2h,
    const float* __restrict__ petab, float* __restrict__ out) {
  __shared__ __align__(16) uint32_t X2[1024 * 32];   // 131072 B
  __shared__ __align__(16) uint32_t Hreg[256 * 32];  // 32768 B (H chunk / redbuf / bufs)

  const int t = threadIdx.x;
  const int b = blockIdx.x;
  const int lane = t & 63;
  const int wv = t >> 6;                  // 0..15
  const bool valid = (t < 1000);
  float* redbuf = (float*)Hreg;           // [32][64] f32 (avg phase)
  float* avgbuf = (float*)(Hreg + 2048);  // 64 f32
  float* attnbuf = (float*)(Hreg + 2112); // 64 f32, 8B-aligned (2112*4 % 8 == 0)

  // ---------------- embed * sqrt(d) + positional encoding -> X2 ----------------
  if (valid) {
    int tok = tokens[b * 1000 + t];
    const float4* ev = (const float4*)(emb + (size_t)tok * 64);
    const int r7 = t & 7;
    if (petab != nullptr) {
      const float4* pv = (const float4*)(petab + (size_t)t * 64);
      #pragma unroll
      for (int q = 0; q < 8; q++) {
        float4 v0 = ev[2 * q], v1 = ev[2 * q + 1];
        float4 p0 = pv[2 * q], p1 = pv[2 * q + 1];
        u32x4 w;
        w[0] = packh2(fmaf(v0.x, 8.f, p0.x), fmaf(v0.y, 8.f, p0.y));
        w[1] = packh2(fmaf(v0.z, 8.f, p0.z), fmaf(v0.w, 8.f, p0.w));
        w[2] = packh2(fmaf(v1.x, 8.f, p1.x), fmaf(v1.y, 8.f, p1.y));
        w[3] = packh2(fmaf(v1.z, 8.f, p1.z), fmaf(v1.w, 8.f, p1.w));
        *(u32x4*)(&X2[t * 32 + ((q ^ r7) << 2)]) = w;
      }
    } else {
      float fs = (float)t;
      #pragma unroll
      for (int q = 0; q < 8; q++) {
        float4 v0 = ev[2 * q], v1 = ev[2 * q + 1];
        float d0 = exp2f(-0.4152410118609203f * (float)(4 * q));
        float d1 = exp2f(-0.4152410118609203f * (float)(4 * q + 1));
        float d2 = exp2f(-0.4152410118609203f * (float)(4 * q + 2));
        float d3 = exp2f(-0.4152410118609203f * (float)(4 * q + 3));
        u32x4 w;
        w[0] = packh2(fmaf(v0.x, 8.f, sinf(fs * d0)), fmaf(v0.y, 8.f, cosf(fs * d0)));
        w[1] = packh2(fmaf(v0.z, 8.f, sinf(fs * d1)), fmaf(v0.w, 8.f, cosf(fs * d1)));
        w[2] = packh2(fmaf(v1.x, 8.f, sinf(fs * d2)), fmaf(v1.y, 8.f, cosf(fs * d2)));
        w[3] = packh2(fmaf(v1.z, 8.f, sinf(fs * d3)), fmaf(v1.w, 8.f, cosf(fs * d3)));
        *(u32x4*)(&X2[t * 32 + ((q ^ r7) << 2)]) = w;
      }
    }
  } else {
    #pragma unroll
    for (int c = 0; c < 32; c += 4)
      *(u32x4*)(&X2[t * 32 + c]) = (u32x4){0u, 0u, 0u, 0u};  // pad rows zero
  }
  __syncthreads();

  const int l15 = lane & 15;
  const int g4 = lane >> 4;               // 0..3
  const int e7 = l15 & 7;                 // (row)&7 for all FF rows of this lane
  const int nt = wv & 3;                  // output-tile (16 cols of W1/W2)
  const int mr = wv >> 2;                 // row-group within a 256-row chunk
  const int cw = 8 * nt + 2 * g4;         // u32-col base of this lane's 4 outputs
  const int cswz = (((cw >> 2) ^ e7) << 2) + (cw & 3);  // swizzled col offset

  #pragma unroll 1
  for (int l = 0; l < NL; l++) {
    const float* n1g = n1_g + l * 64;
    const float* n1b = n1_b + l * 64;
    const float* n2gl = n2_g + l * 64;
    const float* n2bl = n2_b + l * 64;

    // Per-wave weight tile (LICM hoists these to layer scope: 24 VGPRs)
    const f16* w1p = w1h + l * 4096 + (16 * nt + l15) * 64 + 8 * g4;
    f16x8 A10 = *(const f16x8*)(w1p);
    f16x8 A11 = *(const f16x8*)(w1p + 32);
    const f16* w2p = w2h + l * 4096 + (16 * nt + l15) * 64 + 8 * g4;
    f16x8 A20 = *(const f16x8*)(w2p);
    f16x8 A21 = *(const f16x8*)(w2p + 32);
    f32x4 bias1 = *(const f32x4*)(ff1_b + l * 64 + 16 * nt + 4 * g4);
    f32x4 bias2 = *(const f32x4*)(ff2_b + l * 64 + 16 * nt + 4 * g4);

    // ------- avg over sequence: column-parallel partials into redbuf -------
    {
      int cp = t & 31, rg = t >> 5;
      float s0 = 0.f, s1 = 0.f;
      for (int r = rg; r < 1000; r += 32) {
        float2 v = unpackh2(X2[XIU(r, cp)]);
        s0 += v.x;
        s1 += v.y;
      }
      redbuf[rg * 64 + 2 * cp] = s0;
      redbuf[rg * 64 + 2 * cp + 1] = s1;
    }
    __syncthreads();                       // bar 1
    if (t < 64) {
      float ssum = 0.f;
      #pragma unroll
      for (int w = 0; w < 32; w++) ssum += redbuf[w * 64 + t];
      avgbuf[t] = ssum * 1e-3f;
    }
    if (t < 64) {  // attn[o] = lin_b[o] + sum_d avg[d]*lin_w[o][d]
      const float* wr = lin_w + (size_t)(l * 64 + t) * 64;
      float a0 = lin_b[l * 64 + t], a1 = 0.f, a2 = 0.f, a3 = 0.f;
      #pragma unroll
      for (int d = 0; d < 64; d += 4) {
        a0 += avgbuf[d] * wr[d];
        a1 += avgbuf[d + 1] * wr[d + 1];
        a2 += avgbuf[d + 2] * wr[d + 2];
        a3 += avgbuf[d + 3] * wr[d + 3];
      }
      attnbuf[t] = (a0 + a1) + (a2 + a3);
    }
    __syncthreads();                       // bar 2

    // ---------------- LN1 (thread t = row t): Y overwrites X2 ----------------
    if (valid) {
      const float2* at2 = (const float2*)attnbuf;
      const int r7 = t & 7;
      float m0 = 0.f, q0 = 0.f;
      #pragma unroll
      for (int q = 0; q < 8; q++) {
        u32x4 w = *(const u32x4*)(&X2[t * 32 + ((q ^ r7) << 2)]);
        #pragma unroll
        for (int j = 0; j < 4; j++) {
          float2 xv = unpackh2(w[j]);
          float2 at = at2[q * 4 + j];
          float a0 = xv.x + at.x, a1 = xv.y + at.y;
          m0 += a0 + a1;
          q0 = fmaf(a0, a0, q0);
          q0 = fmaf(a1, a1, q0);
        }
      }
      float mu = m0 * (1.0f / 64.0f);
      float var = q0 * (1.0f / 64.0f) - mu * mu;
      float rs = rsqrtf(var + 1e-5f);
      #pragma unroll
      for (int q = 0; q < 8; q++) {
        u32x4 w = *(const u32x4*)(&X2[t * 32 + ((q ^ r7) << 2)]);
        u32x4 o;
        #pragma unroll
        for (int j = 0; j < 4; j++) {
          float2 xv = unpackh2(w[j]);
          float2 at = at2[q * 4 + j];
          int d = (q * 4 + j) * 2;
          float a0 = xv.x + at.x, a1 = xv.y + at.y;
          o[j] = packh2(fmaf((a0 - mu) * rs, n1g[d], n1b[d]),
                        fmaf((a1 - mu) * rs, n1g[d + 1], n1b[d + 1]));
        }
        *(u32x4*)(&X2[t * 32 + ((q ^ r7) << 2)]) = o;
      }
    }
    __syncthreads();                       // bar 3: Y visible to FF waves

    // ---------------- FF: 4 chunks of 256 rows ----------------
    #pragma unroll 1
    for (int i = 0; i < 4; i++) {
      const int s0 = 256 * i + 64 * mr;
      // --- mm1: H^T(tile nt) = W1 * Y^T for this wave's 64 rows ---
      #pragma unroll 2
      for (int sb = 0; sb < 4; sb++) {
        const int s = s0 + 16 * sb + l15;
        u32x4 b0 = *(const u32x4*)(&X2[s * 32 + ((g4 ^ e7) << 2)]);
        u32x4 b1 = *(const u32x4*)(&X2[s * 32 + (((4 + g4) ^ e7) << 2)]);
        f32x4 acc = bias1;
        acc = __builtin_amdgcn_mfma_f32_16x16x32_f16(
            A10, __builtin_bit_cast(f16x8, b0), acc, 0, 0, 0);
        acc = __builtin_amdgcn_mfma_f32_16x16x32_f16(
            A11, __builtin_bit_cast(f16x8, b1), acc, 0, 0, 0);
        const int hr = 64 * mr + 16 * sb + l15;   // chunk-local row
        u32x2 hp;
        hp[0] = packh2(fmaxf(acc[0], 0.f), fmaxf(acc[1], 0.f));
        hp[1] = packh2(fmaxf(acc[2], 0.f), fmaxf(acc[3], 0.f));
        *(u32x2*)(&Hreg[hr * 32 + cswz]) = hp;
      }
      __syncthreads();                     // H chunk complete
      // --- mm2: T^T(tile nt) = W2 * H + b2 + Y, write back to X2 ---
      #pragma unroll 2
      for (int sb = 0; sb < 4; sb++) {
        const int s = s0 + 16 * sb + l15;
        const int hr = 64 * mr + 16 * sb + l15;
        u32x4 h0 = *(const u32x4*)(&Hreg[hr * 32 + ((g4 ^ e7) << 2)]);
        u32x4 h1 = *(const u32x4*)(&Hreg[hr * 32 + (((4 + g4) ^ e7) << 2)]);
        u32x2 ry = *(const u32x2*)(&X2[s * 32 + cswz]);
        float2 r0 = unpackh2(ry[0]), r1 = unpackh2(ry[1]);
        f32x4 acc = bias2;
        acc[0] += r0.x;
        acc[1] += r0.y;
        acc[2] += r1.x;
        acc[3] += r1.y;
        acc = __builtin_amdgcn_mfma_f32_16x16x32_f16(
            A20, __builtin_bit_cast(f16x8, h0), acc, 0, 0, 0);
        acc = __builtin_amdgcn_mfma_f32_16x16x32_f16(
            A21, __builtin_bit_cast(f16x8, h1), acc, 0, 0, 0);
        u32x2 tw;
        tw[0] = packh2(acc[0], acc[1]);
        tw[1] = packh2(acc[2], acc[3]);
        *(u32x2*)(&X2[s * 32 + cswz]) = tw;
      }
      __syncthreads();                     // T chunk visible; Hreg reusable
    }

    // ---------------- LN2 (thread-per-row) over T in X2; pads zeroed ----------------
    if (valid) {
      const int r7 = t & 7;
      float m0 = 0.f, q0 = 0.f;
      #pragma unroll
      for (int q = 0; q < 8; q++) {
        u32x4 w = *(const u32x4*)(&X2[t * 32 + ((q ^ r7) << 2)]);
        #pragma unroll
        for (int j = 0; j < 4; j++) {
          float2 tv = unpackh2(w[j]);
          m0 += tv.x + tv.y;
          q0 = fmaf(tv.x, tv.x, q0);
          q0 = fmaf(tv.y, tv.y, q0);
        }
      }
      float mu2 = m0 * (1.0f / 64.0f);
      float var2 = q0 * (1.0f / 64.0f) - mu2 * mu2;
      float rs2 = rsqrtf(var2 + 1e-5f);
      #pragma unroll
      for (int q = 0; q < 8; q++) {
        u32x4 w = *(const u32x4*)(&X2[t * 32 + ((q ^ r7) << 2)]);
        u32x4 o;
        #pragma unroll
        for (int j = 0; j < 4; j++) {
          float2 tv = unpackh2(w[j]);
          int d = (q * 4 + j) * 2;
          o[j] = packh2(fmaf((tv.x - mu2) * rs2, n2gl[d], n2bl[d]),
                        fmaf((tv.y - mu2) * rs2, n2gl[d + 1], n2bl[d + 1]));
        }
        *(u32x4*)(&X2[t * 32 + ((q ^ r7) << 2)]) = o;
      }
    } else {
      #pragma unroll
      for (int c = 0; c < 32; c += 4)
        *(u32x4*)(&X2[t * 32 + c]) = (u32x4){0u, 0u, 0u, 0u};  // re-zero pads
    }
    __syncthreads();                       // layer complete
  }

  // ---------------- output projection [B,S,2] ----------------
  if (valid) {
    const int r7 = t & 7;
    float a0 = out_b[0], a1 = out_b[1];
    #pragma unroll
    for (int q = 0; q < 8; q++) {
      u32x4 w = *(const u32x4*)(&X2[t * 32 + ((q ^ r7) << 2)]);
      #pragma unroll
      for (int j = 0; j < 4; j++) {
        float2 xv = unpackh2(w[j]);
        int d = (q * 4 + j) * 2;
        a0 += xv.x * out_w[d] + xv.y * out_w[d + 1];
        a1 += xv.x * out_w[64 + d] + xv.y * out_w[64 + d + 1];
      }
    }
    *(float2*)(out + (size_t)(b * 1000 + t) * 2) = make_float2(a0, a1);
  }
}

extern "C" void kernel_launch(void* const* d_in, const int* in_sizes, int n_in,
                              void* d_out, int out_size, void* d_ws, size_t ws_size,
                              hipStream_t stream) {
  const int* tokens = (const int*)d_in[0];
  const float* emb = (const float*)d_in[1];
  const float* lin_w = (const float*)d_in[2];
  const float* lin_b = (const float*)d_in[3];
  const float* ff1_w = (const float*)d_in[4];
  const float* ff1_b = (const float*)d_in[5];
  const float* ff2_w = (const float*)d_in[6];
  const float* ff2_b = (const float*)d_in[7];
  const float* n1_g = (const float*)d_in[8];
  const float* n1_b = (const float*)d_in[9];
  const float* n2_g = (const float*)d_in[10];
  const float* n2_b = (const float*)d_in[11];
  const float* out_w = (const float*)d_in[12];
  const float* out_b = (const float*)d_in[13];
  float* out = (float*)d_out;

  f16* w1h = (f16*)d_ws;                         // 32 KiB
  f16* w2h = w1h + 16384;                        // 32 KiB
  float* petab = (float*)((char*)d_ws + 65536);  // 250 KiB (1000*64 f32)
  const size_t need = 65536 + 64000 * 4;
  const bool use_pe = (ws_size >= need);
  float* pe_arg = use_pe ? petab : nullptr;

  int pack_threads = 32768 + (use_pe ? 64000 : 0);
  int pack_blocks = (pack_threads + 255) / 256;
  pack_weights_kernel<<<pack_blocks, 256, 0, stream>>>(ff1_w, ff2_w, w1h, w2h, pe_arg);
  aat_kernel<<<512, TPB, 0, stream>>>(tokens, emb, lin_w, lin_b, ff1_b, ff2_b,
                                      n1_g, n1_b, n2_g, n2_b, out_w, out_b,
                                      w1h, w2h, pe_arg, out);
}